// Round 10
// baseline (518.699 us; speedup 1.0000x reference)
//
#include <hip/hip_runtime.h>
#include <math.h>

#define NEG_SLOPE 0.2f
#define EPSF 1e-16f

typedef _Float16 h2v __attribute__((ext_vector_type(2)));
typedef _Float16 h4v __attribute__((ext_vector_type(4)));
typedef _Float16 h8v __attribute__((ext_vector_type(8)));
typedef float f4v __attribute__((ext_vector_type(4)));

#define AS1 __attribute__((address_space(1)))
#define AS3 __attribute__((address_space(3)))

__device__ __forceinline__ void gll16(const void* g, void* l) {
  __builtin_amdgcn_global_load_lds((AS1 void*)g, (AS3 void*)l, 16, 0, 0);
}

// ---------------- CSR build ----------------

__global__ void hist_kernel(const int* __restrict__ dst, int* __restrict__ counts, int E) {
  int t = blockIdx.x * 256 + threadIdx.x;
  if (t < E) atomicAdd(&counts[dst[t]], 1);
}

__global__ void scan1(const int* __restrict__ counts, int* __restrict__ offs,
                      int* __restrict__ bsum, int N) {
  __shared__ int sd[1024];
  int tid = threadIdx.x;
  int i = blockIdx.x * 1024 + tid;
  int v = (i < N) ? counts[i] : 0;
  sd[tid] = v;
  __syncthreads();
  for (int s = 1; s < 1024; s <<= 1) {
    int tv = (tid >= s) ? sd[tid - s] : 0;
    __syncthreads();
    sd[tid] += tv;
    __syncthreads();
  }
  if (i < N) offs[i] = sd[tid] - v;  // local exclusive
  if (tid == 1023) bsum[blockIdx.x] = sd[1023];
}

__global__ void scan2(int* __restrict__ bsum, int* __restrict__ offs, int nb, int N, int E) {
  if (threadIdx.x == 0) {
    int r = 0;
    for (int i = 0; i < nb; i++) { int v = bsum[i]; bsum[i] = r; r += v; }
    offs[N] = E;
  }
}

__global__ void scan3(int* __restrict__ offs, const int* __restrict__ bsum, int N) {
  int i = blockIdx.x * 1024 + threadIdx.x;
  if (i < N) offs[i] += bsum[blockIdx.x];
}

__global__ void scatter_kernel(const int* __restrict__ src, const int* __restrict__ dst,
                               const int* __restrict__ off, int* __restrict__ cur,
                               int* __restrict__ srcp, int E) {
  int t = blockIdx.x * 256 + threadIdx.x;
  if (t < E) {
    int d = dst[t];
    int p = off[d] + atomicAdd(&cur[d], 1);
    srcp[p] = src[t];
  }
}

// ---------------- fp32 -> f16 converts ----------------

__global__ void convX(const float* __restrict__ x, _Float16* __restrict__ xh, int n4) {
  int i = blockIdx.x * 256 + threadIdx.x;
  if (i >= n4) return;
  float4 v = ((const float4*)x)[i];
  h4v h;
  h[0] = (_Float16)v.x; h[1] = (_Float16)v.y;
  h[2] = (_Float16)v.z; h[3] = (_Float16)v.w;
  ((h4v*)xh)[i] = h;
}

// W [K][512] f32 -> Wt [512][K] f16 transposed, coalesced via LDS tile.
__global__ void convW(const float* __restrict__ W, _Float16* __restrict__ Th, int K) {
  __shared__ float tile[32][33];
  int bx = blockIdx.x * 32;  // output-col base (N=512 dim)
  int by = blockIdx.y * 32;  // k base
  int tx = threadIdx.x, ty = threadIdx.y;
#pragma unroll
  for (int i = 0; i < 32; i += 8)
    tile[ty + i][tx] = W[(size_t)(by + ty + i) * 512 + bx + tx];
  __syncthreads();
#pragma unroll
  for (int i = 0; i < 32; i += 8)
    Th[(size_t)(bx + ty + i) * K + by + tx] = (_Float16)tile[tx][ty + i];
}

// Ws3 [512][16] -> Bt [16][512]
__global__ void convW3(const float* __restrict__ W, _Float16* __restrict__ Th) {
  int t = blockIdx.x * 256 + threadIdx.x;
  if (t >= 512 * 16) return;
  int k = t >> 4, c = t & 15;
  Th[c * 512 + k] = (_Float16)W[t];
}

// ---------------- f16 MFMA GEMM: A-direct-from-L2, B-in-LDS, fused als ----------------
// C[M,512](f16) = A[M,K](f16) @ B[K,512]; B transposed [512][K] f16.
// BM=256 (4 waves x 64-row bands), BN=64 (one col-strip), BK=32.
// A fragments: direct global->VGPR 16B loads (64B line fully used by 4 kg lanes);
// A-panel L2-resident, reused by the 8 col-strip blocks grouped adjacently (XCD swizzle).
// B tile: 4KB/step staged via global_load_lds, 3 buffers (12KB), 1 s_barrier/step,
// order-robust counted wait vmcnt(5) = retire the 2-steps-old {B(1),A(4)} quintuple.
// XOR slot swizzle (slot = kg ^ (rr&3) ^ ((rr>>2)&3)) -> 2-way LDS reads (free, m136);
// stage applies the same involution on the GLOBAL source (both-sides rule).
// Fused: als8[row*8 + strip] = sum_col C[row,col]*a_s[col] (per-strip partial; wave owns
// its rows exclusively -> 16-lane shfl reduce only, no LDS combine).

template <int K>
__global__ __launch_bounds__(256) void gemm_f16(
    const _Float16* __restrict__ A, const _Float16* __restrict__ Bh,
    const float* __restrict__ a_s, _Float16* __restrict__ C,
    float* __restrict__ als8, int M) {
  __shared__ __align__(16) char sm[12288];  // 3 x 4KB B-tiles
  constexpr int T = K / 32;
  const int t = threadIdx.x;
  const int w = t >> 6, l = t & 63;
  const int kg = l >> 4, rr = l & 15;

  // XCD swizzle (nwg % 8 == 0): contiguous wgid chunk per XCD; wgid>>3 = row-panel,
  // wgid&7 = col-strip -> 8 strips of one panel adjacent -> A-panel L2 reuse.
  const int nwg = gridDim.x;
  const int orig = blockIdx.x;
  const int wgid = (orig & 7) * (nwg >> 3) + (orig >> 3);
  const size_t tm = (size_t)(wgid >> 3) * 256;
  const int strip = wgid & 7;
  const size_t cn = (size_t)strip * 64;

  const size_t arow = tm + (size_t)w * 64;  // wave's row band

  // B stage mapping: thread t -> LDS slot t*16 (linear, wave-uniform+lane*16);
  // source k-part pre-swizzled so READ-side XOR lands on the right data.
  const int br = t >> 2;
  const int bkp = (t & 3) ^ (br & 3) ^ ((br >> 2) & 3);
  const _Float16* bsrc = Bh + (cn + br) * K + bkp * 8;
  char* bdst = sm + t * 16;
  const int bslot = kg ^ (rr & 3) ^ ((rr >> 2) & 3);  // read-side slot

  f4v acc[4][4];
#pragma unroll
  for (int i = 0; i < 4; i++)
#pragma unroll
    for (int j = 0; j < 4; j++) acc[i][j] = (f4v){0.f, 0.f, 0.f, 0.f};

  h8v a0[4], a1[4];
  // prologue: per-wave issue order [B(0), A(0)x4, B(1), A(1)x4] -> 10 outstanding
  gll16(bsrc, bdst);
#pragma unroll
  for (int i = 0; i < 4; i++)
    a0[i] = *(const h8v*)&A[(arow + i * 16 + rr) * K + kg * 8];
  gll16(bsrc + 32, bdst + 4096);
#pragma unroll
  for (int i = 0; i < 4; i++)
    a1[i] = *(const h8v*)&A[(arow + i * 16 + rr) * K + 32 + kg * 8];

#pragma unroll
  for (int ts = 0; ts < T; ts++) {
    const int kt = ts * 32;
    if (ts + 1 < T) {
      asm volatile("s_waitcnt vmcnt(5)" ::: "memory");  // retire 2-steps-old {B,A}
    } else {
      asm volatile("s_waitcnt vmcnt(0)" ::: "memory");
    }
    __builtin_amdgcn_sched_barrier(0);
    __builtin_amdgcn_s_barrier();  // all waves' B(ts) landed; readers of reused buf done

    if (ts + 2 < T) gll16(bsrc + kt + 64, sm + ((ts + 2) % 3) * 4096 + t * 16);

    const char* base = sm + (ts % 3) * 4096;
    h8v bf[4];
#pragma unroll
    for (int j = 0; j < 4; j++)
      bf[j] = *(const h8v*)(base + (j * 16 + rr) * 64 + bslot * 16);

    h8v(&ar)[4] = (ts & 1) ? a1 : a0;
#pragma unroll
    for (int i = 0; i < 4; i++)
#pragma unroll
      for (int j = 0; j < 4; j++)
        acc[i][j] = __builtin_amdgcn_mfma_f32_16x16x32_f16(ar[i], bf[j], acc[i][j], 0, 0, 0);

    // refill the just-consumed parity buffer with A(ts+2)
    if (ts + 2 < T) {
#pragma unroll
      for (int i = 0; i < 4; i++)
        ar[i] = *(const h8v*)&A[(arow + i * 16 + rr) * K + kt + 64 + kg * 8];
    }
  }

  // epilogue: C/D layout col=lane&15, row=(lane>>4)*4+reg
  float sp[16];
#pragma unroll
  for (int k = 0; k < 16; k++) sp[k] = 0.f;
#pragma unroll
  for (int i = 0; i < 4; i++) {
#pragma unroll
    for (int j = 0; j < 4; j++) {
      int col = j * 16 + rr;
      float aw = a_s[cn + col];
#pragma unroll
      for (int r2 = 0; r2 < 4; r2++) {
        float v = acc[i][j][r2];
        size_t row = arow + i * 16 + kg * 4 + r2;
        if (row < (size_t)M) C[row * 512 + cn + col] = (_Float16)v;
        sp[i * 4 + r2] += v * aw;
      }
    }
  }
#pragma unroll
  for (int o = 1; o < 16; o <<= 1)
#pragma unroll
    for (int k = 0; k < 16; k++) sp[k] += __shfl_xor(sp[k], o);
  if (rr == 0) {
#pragma unroll
    for (int k = 0; k < 16; k++) {
      size_t row = arow + (k >> 2) * 16 + kg * 4 + (k & 3);
      if (row < (size_t)M) als8[row * 8 + strip] = sp[k];
    }
  }
}

// ---------------- layer-3 projection via MFMA + fused als3 ----------------
// C[M,16](f32) = A[M,512] @ B[512,16]; one wave per 16-row tile; B^T [16][512] f16.

__global__ __launch_bounds__(256) void gemm3(const _Float16* __restrict__ A,
                                             const _Float16* __restrict__ Bth,
                                             const float* __restrict__ as3,
                                             float* __restrict__ C,
                                             float* __restrict__ als, int M) {
  int wv = threadIdx.x >> 6, l = threadIdx.x & 63;
  size_t tm = ((size_t)blockIdx.x * 4 + wv) * 16;
  if (tm >= (size_t)M) return;
  int rr = l & 15, kg = l >> 4;
  f4v acc = (f4v){0.f, 0.f, 0.f, 0.f};
  for (int kt = 0; kt < 512; kt += 32) {
    int ka = kt + kg * 8;
    h8v a_h = *(const h8v*)&A[(tm + rr) * 512 + ka];
    h8v b_h = *(const h8v*)&Bth[rr * 512 + ka];
    acc = __builtin_amdgcn_mfma_f32_16x16x32_f16(a_h, b_h, acc, 0, 0, 0);
  }
  float aw = as3[rr];
  float s[4];
#pragma unroll
  for (int r = 0; r < 4; r++) s[r] = acc[r] * aw;
#pragma unroll
  for (int o = 1; o < 16; o <<= 1)
#pragma unroll
    for (int r = 0; r < 4; r++) s[r] += __shfl_xor(s[r], o);
#pragma unroll
  for (int r = 0; r < 4; r++) {
    size_t row = tm + kg * 4 + r;
    if (row < (size_t)M) {
      C[row * 16 + rr] = acc[r];
      if (rr == 0) als[row] = s[r];
    }
  }
}

// ---------------- wsd[k][h] = sum_c Wd[k][h*C+c] * a_d[h][c] ----------------

__global__ void wsd_kernel(const float* __restrict__ Wd, const float* __restrict__ a_d,
                           float* __restrict__ wsd, int K, int H, int C) {
  int g = (blockIdx.x * 256 + threadIdx.x) >> 4;
  int l16 = threadIdx.x & 15;
  if (g >= K * H) return;
  int k = g / H, h = g - k * H;
  int ce = C >> 4;
  float s = 0.f;
  for (int j = 0; j < ce; j++) {
    int c = l16 * ce + j;
    s += Wd[(size_t)k * (H * C) + h * C + c] * a_d[h * C + c];
  }
#pragma unroll
  for (int o = 1; o < 16; o <<= 1) s += __shfl_xor(s, o);
  if (l16 == 0) wsd[k * H + h] = s;
}

// ---------------- per-edge normalized softmax weights (ald fused in) ----------------
// H=4: one wave per node. lane = e*4+h. ald computed in-register from own h-row.
// als is strip-partial [N,8]: als(n,h) = als8[n*8+2h] + als8[n*8+2h+1].

__device__ __forceinline__ float als4(const float* __restrict__ a8, int s, int h) {
  float2 v = *(const float2*)&a8[(size_t)s * 8 + 2 * h];
  return v.x + v.y;
}

template <int K>
__global__ void wgt4_kernel(const float* __restrict__ als8, const _Float16* __restrict__ hin,
                            const float* __restrict__ wsd, const int* __restrict__ off,
                            const int* __restrict__ srcp, _Float16* __restrict__ wgt, int N) {
  int wid = threadIdx.x >> 6, lane = threadIdx.x & 63;
  int n = blockIdx.x * 4 + wid;
  if (n >= N) return;
  int p0 = off[n], deg = off[n + 1] - p0;
  if (deg == 0) return;

  // ald for own node: lane covers K/64 consecutive k
  float d0 = 0.f, d1 = 0.f, d2 = 0.f, d3 = 0.f;
  constexpr int KP = K / 64;
  {
    int k0 = lane * KP;
    if constexpr (K == 512) {
      h8v qv = *(const h8v*)&hin[(size_t)n * K + k0];
#pragma unroll
      for (int j = 0; j < 8; j++) {
        float xv = (float)qv[j];
        float4 wv = *(const float4*)&wsd[(k0 + j) * 4];
        d0 += xv * wv.x; d1 += xv * wv.y; d2 += xv * wv.z; d3 += xv * wv.w;
      }
    } else {
      h2v qv = *(const h2v*)&hin[(size_t)n * K + k0];
#pragma unroll
      for (int j = 0; j < KP; j++) {
        float xv = (float)qv[j];
        float4 wv = *(const float4*)&wsd[(k0 + j) * 4];
        d0 += xv * wv.x; d1 += xv * wv.y; d2 += xv * wv.z; d3 += xv * wv.w;
      }
    }
#pragma unroll
    for (int o = 1; o < 64; o <<= 1) {
      d0 += __shfl_xor(d0, o); d1 += __shfl_xor(d1, o);
      d2 += __shfl_xor(d2, o); d3 += __shfl_xor(d3, o);
    }
  }
  int h = lane & 3, e = lane >> 2;
  float aldn = (h == 0) ? d0 : (h == 1) ? d1 : (h == 2) ? d2 : d3;

  float ev0 = -1e30f;
  if (e < deg) {
    float v = als4(als8, srcp[p0 + e], h) + aldn;
    ev0 = (v > 0.f) ? v : NEG_SLOPE * v;
  }
  float m = ev0;
  for (int base = 16; base < deg; base += 16) {
    float ev = -1e30f;
    if (base + e < deg) {
      float v = als4(als8, srcp[p0 + base + e], h) + aldn;
      ev = (v > 0.f) ? v : NEG_SLOPE * v;
    }
    m = fmaxf(m, ev);
  }
#pragma unroll
  for (int o = 4; o < 64; o <<= 1) m = fmaxf(m, __shfl_xor(m, o));
  float den = (e < deg) ? __expf(ev0 - m) : 0.f;
  for (int base = 16; base < deg; base += 16) {
    if (base + e < deg) {
      float v = als4(als8, srcp[p0 + base + e], h) + aldn;
      v = (v > 0.f) ? v : NEG_SLOPE * v;
      den += __expf(v - m);
    }
  }
#pragma unroll
  for (int o = 4; o < 64; o <<= 1) den += __shfl_xor(den, o);
  float rw = 1.f / (den + EPSF);
  if (e < deg) wgt[(size_t)(p0 + e) * 4 + h] = (_Float16)(__expf(ev0 - m) * rw);
  for (int base = 16; base < deg; base += 16) {
    if (base + e < deg) {
      float v = als4(als8, srcp[p0 + base + e], h) + aldn;
      v = (v > 0.f) ? v : NEG_SLOPE * v;
      wgt[(size_t)(p0 + base + e) * 4 + h] = (_Float16)(__expf(v - m) * rw);
    }
  }
}

// H=1: one wave per node, lane = edge slot; ald fused (own h-row · wsd). als flat [N].
__global__ void wgt1_kernel(const float* __restrict__ als, const _Float16* __restrict__ hin,
                            const float* __restrict__ wsd, const int* __restrict__ off,
                            const int* __restrict__ srcp, _Float16* __restrict__ wgt, int N) {
  int wid = threadIdx.x >> 6, lane = threadIdx.x & 63;
  int n = blockIdx.x * 4 + wid;
  if (n >= N) return;
  int p0 = off[n], deg = off[n + 1] - p0;
  if (deg == 0) return;

  float aldn = 0.f;
  {
    h8v qv = *(const h8v*)&hin[(size_t)n * 512 + lane * 8];
#pragma unroll
    for (int j = 0; j < 8; j++) aldn += (float)qv[j] * wsd[lane * 8 + j];
#pragma unroll
    for (int o = 1; o < 64; o <<= 1) aldn += __shfl_xor(aldn, o);
  }

  float ev0 = -1e30f;
  if (lane < deg) {
    float v = als[srcp[p0 + lane]] + aldn;
    ev0 = (v > 0.f) ? v : NEG_SLOPE * v;
  }
  float m = ev0;
  for (int base = 64; base < deg; base += 64) {
    float ev = -1e30f;
    if (base + lane < deg) {
      float v = als[srcp[p0 + base + lane]] + aldn;
      ev = (v > 0.f) ? v : NEG_SLOPE * v;
    }
    m = fmaxf(m, ev);
  }
#pragma unroll
  for (int o = 1; o < 64; o <<= 1) m = fmaxf(m, __shfl_xor(m, o));
  float den = (lane < deg) ? __expf(ev0 - m) : 0.f;
  for (int base = 64; base < deg; base += 64) {
    if (base + lane < deg) {
      float v = als[srcp[p0 + base + lane]] + aldn;
      v = (v > 0.f) ? v : NEG_SLOPE * v;
      den += __expf(v - m);
    }
  }
#pragma unroll
  for (int o = 1; o < 64; o <<= 1) den += __shfl_xor(den, o);
  float rw = 1.f / (den + EPSF);
  if (lane < deg) wgt[p0 + lane] = (_Float16)(__expf(ev0 - m) * rw);
  for (int base = 64; base < deg; base += 64) {
    if (base + lane < deg) {
      float v = als[srcp[p0 + base + lane]] + aldn;
      v = (v > 0.f) ? v : NEG_SLOPE * v;
      wgt[p0 + base + lane] = (_Float16)(__expf(v - m) * rw);
    }
  }
}

// ---------------- aggregation: single weighted-gather pass ----------------
// layers 1,2: one 128-thread block per node, thread t handles channels 4t..4t+3.

__global__ __launch_bounds__(128) void agg512(
    const _Float16* __restrict__ xs, const _Float16* __restrict__ wgt,
    const int* __restrict__ off, const int* __restrict__ srcp,
    const float* __restrict__ bias, _Float16* __restrict__ oh, int N) {
  int n = blockIdx.x;
  int t = threadIdx.x;
  int h = t >> 5;  // channel 4t -> head 4t/128
  int p0 = off[n], p1 = off[n + 1];
  float a0 = 0.f, a1 = 0.f, a2 = 0.f, a3 = 0.f;
  float c0 = 0.f, c1 = 0.f, c2 = 0.f, c3 = 0.f;
  int p = p0;
  for (; p + 1 < p1; p += 2) {
    int s0 = srcp[p], s1 = srcp[p + 1];
    float w0 = (float)wgt[(size_t)p * 4 + h];
    float w1 = (float)wgt[(size_t)(p + 1) * 4 + h];
    h4v v0 = *(const h4v*)&xs[(size_t)s0 * 512 + 4 * t];
    h4v v1 = *(const h4v*)&xs[(size_t)s1 * 512 + 4 * t];
    a0 += w0 * (float)v0[0]; a1 += w0 * (float)v0[1];
    a2 += w0 * (float)v0[2]; a3 += w0 * (float)v0[3];
    c0 += w1 * (float)v1[0]; c1 += w1 * (float)v1[1];
    c2 += w1 * (float)v1[2]; c3 += w1 * (float)v1[3];
  }
  if (p < p1) {
    int s0 = srcp[p];
    float w0 = (float)wgt[(size_t)p * 4 + h];
    h4v v0 = *(const h4v*)&xs[(size_t)s0 * 512 + 4 * t];
    a0 += w0 * (float)v0[0]; a1 += w0 * (float)v0[1];
    a2 += w0 * (float)v0[2]; a3 += w0 * (float)v0[3];
  }
  a0 += c0; a1 += c1; a2 += c2; a3 += c3;
  float4 b = *(const float4*)&bias[4 * t];
  a0 = fmaxf(a0 + b.x, 0.f); a1 = fmaxf(a1 + b.y, 0.f);
  a2 = fmaxf(a2 + b.z, 0.f); a3 = fmaxf(a3 + b.w, 0.f);
  h4v wh;
  wh[0] = (_Float16)a0; wh[1] = (_Float16)a1;
  wh[2] = (_Float16)a2; wh[3] = (_Float16)a3;
  *(h4v*)&oh[(size_t)n * 512 + 4 * t] = wh;
}

// layer 3: H=1, C=16, no relu, f32 out. 16 nodes per block.
__global__ void agg16(const float* __restrict__ xs3, const _Float16* __restrict__ wgt,
                      const int* __restrict__ off, const int* __restrict__ srcp,
                      const float* __restrict__ bias, float* __restrict__ out, int N) {
  int g = threadIdx.x >> 4, c = threadIdx.x & 15;
  int n = blockIdx.x * 16 + g;
  if (n >= N) return;
  int p0 = off[n], p1 = off[n + 1];
  float acc = 0.f;
  for (int p = p0; p < p1; p++)
    acc += (float)wgt[p] * xs3[(size_t)srcp[p] * 16 + c];
  out[(size_t)n * 16 + c] = acc + bias[c];
}

// ---------------- launch ----------------

extern "C" void kernel_launch(void* const* d_in, const int* in_sizes, int n_in,
                              void* d_out, int out_size, void* d_ws, size_t ws_size,
                              hipStream_t stream) {
  const float* x   = (const float*)d_in[0];
  const int*   ei  = (const int*)d_in[1];
  const float* Ws1 = (const float*)d_in[2];
  const float* Wd1 = (const float*)d_in[3];
  const float* as1 = (const float*)d_in[4];
  const float* ad1 = (const float*)d_in[5];
  const float* b1  = (const float*)d_in[6];
  const float* Ws2 = (const float*)d_in[7];
  const float* Wd2 = (const float*)d_in[8];
  const float* as2 = (const float*)d_in[9];
  const float* ad2 = (const float*)d_in[10];
  const float* b2  = (const float*)d_in[11];
  const float* Ws3 = (const float*)d_in[12];
  const float* Wd3 = (const float*)d_in[13];
  const float* as3 = (const float*)d_in[14];
  const float* ad3 = (const float*)d_in[15];
  const float* b3  = (const float*)d_in[16];

  const int N = in_sizes[0] / 128;  // 50000
  const int E = in_sizes[1] / 2;    // 400000
  const int* src = ei;
  const int* dst = ei + E;

  // workspace layout (bytes), total ~113 MB; all offsets 16B-aligned
  char* w = (char*)d_ws;
  _Float16* xs     = (_Float16*)(w + 0);           // [N,512] f16
  _Float16* hbuf   = (_Float16*)(w + 51200000);    // [N,512] f16 ([N,128] x_f16 early)
  float*    als8   = (float*)(w + 102400000);      // [N,8] strip partials (layer3: [N] flat)
  float*    xs3    = (float*)(w + 104000000);      // [N,16] f32
  _Float16* wgt    = (_Float16*)(w + 107200000);   // [E,4] f16
  int*      counts = (int*)(w + 110400000);        // [N]
  int*      cur    = (int*)(w + 110600000);        // [N]
  int*      offs   = (int*)(w + 110800000);        // [N+1]
  int*      bsum   = (int*)(w + 111000192);        // [~49]
  int*      srcp   = (int*)(w + 111004288);        // [E]
  float*    wsd    = (float*)(w + 112604288);      // [512,4]
  _Float16* wt_hi  = (_Float16*)(w + 112612480);   // [512,512] f16 (B^T)
  _Float16* wt3_hi = (_Float16*)(w + 113136768);   // [16,512] f16

  // ---- CSR build ----
  hipMemsetAsync(counts, 0, 2 * (size_t)N * 4, stream);  // counts + cur contiguous
  hist_kernel<<<(E + 255) / 256, 256, 0, stream>>>(dst, counts, E);
  int nb = (N + 1023) / 1024;
  scan1<<<nb, 1024, 0, stream>>>(counts, offs, bsum, N);
  scan2<<<1, 64, 0, stream>>>(bsum, offs, nb, N, E);
  scan3<<<nb, 1024, 0, stream>>>(offs, bsum, N);
  scatter_kernel<<<(E + 255) / 256, 256, 0, stream>>>(src, dst, offs, cur, srcp, E);

  int ggrid = ((N + 255) / 256) * 8;  // 196 row-panels x 8 col-strips; swizzle in-kernel
  dim3 cwb(32, 8);
  int nwb = (N + 3) / 4;

  // ---- layer 1 (K=128) ----
  convX<<<(N * 128 / 4 + 255) / 256, 256, 0, stream>>>(x, hbuf, N * 128 / 4);
  wsd_kernel<<<(128 * 4 * 16 + 255) / 256, 256, 0, stream>>>(Wd1, ad1, wsd, 128, 4, 128);
  convW<<<dim3(16, 4), cwb, 0, stream>>>(Ws1, wt_hi, 128);
  gemm_f16<128><<<ggrid, 256, 0, stream>>>(hbuf, wt_hi, as1, xs, als8, N);
  wgt4_kernel<128><<<nwb, 256, 0, stream>>>(als8, hbuf, wsd, offs, srcp, wgt, N);
  agg512<<<N, 128, 0, stream>>>(xs, wgt, offs, srcp, b1, hbuf, N);

  // ---- layer 2 (K=512) ----
  wsd_kernel<<<(512 * 4 * 16 + 255) / 256, 256, 0, stream>>>(Wd2, ad2, wsd, 512, 4, 128);
  convW<<<dim3(16, 16), cwb, 0, stream>>>(Ws2, wt_hi, 512);
  gemm_f16<512><<<ggrid, 256, 0, stream>>>(hbuf, wt_hi, as2, xs, als8, N);
  wgt4_kernel<512><<<nwb, 256, 0, stream>>>(als8, hbuf, wsd, offs, srcp, wgt, N);
  agg512<<<N, 128, 0, stream>>>(xs, wgt, offs, srcp, b2, hbuf, N);

  // ---- layer 3 (K=512, N=16, H=1) ----
  wsd_kernel<<<(512 * 16 + 255) / 256, 256, 0, stream>>>(Wd3, ad3, wsd, 512, 1, 16);
  convW3<<<32, 256, 0, stream>>>(Ws3, wt3_hi);
  gemm3<<<(N / 16 + 4) / 4, 256, 0, stream>>>(hbuf, wt3_hi, as3, xs3, als8, N);
  wgt1_kernel<<<nwb, 256, 0, stream>>>(als8, hbuf, wsd, offs, srcp, wgt, N);
  agg16<<<(N + 15) / 16, 256, 0, stream>>>(xs3, wgt, offs, srcp, b3, (float*)d_out, N);
}

// Round 11
// 489.496 us; speedup vs baseline: 1.0597x; 1.0597x over previous
//
#include <hip/hip_runtime.h>
#include <math.h>

#define NEG_SLOPE 0.2f
#define EPSF 1e-16f

typedef _Float16 h2v __attribute__((ext_vector_type(2)));
typedef _Float16 h4v __attribute__((ext_vector_type(4)));
typedef _Float16 h8v __attribute__((ext_vector_type(8)));
typedef float f4v __attribute__((ext_vector_type(4)));

#define AS1 __attribute__((address_space(1)))
#define AS3 __attribute__((address_space(3)))

__device__ __forceinline__ void gll16(const void* g, void* l) {
  __builtin_amdgcn_global_load_lds((AS1 void*)g, (AS3 void*)l, 16, 0, 0);
}

// ---------------- CSR build ----------------

__global__ void hist_kernel(const int* __restrict__ dst, int* __restrict__ counts, int E) {
  int t = blockIdx.x * 256 + threadIdx.x;
  if (t < E) atomicAdd(&counts[dst[t]], 1);
}

__global__ void scan1(const int* __restrict__ counts, int* __restrict__ offs,
                      int* __restrict__ bsum, int N) {
  __shared__ int sd[1024];
  int tid = threadIdx.x;
  int i = blockIdx.x * 1024 + tid;
  int v = (i < N) ? counts[i] : 0;
  sd[tid] = v;
  __syncthreads();
  for (int s = 1; s < 1024; s <<= 1) {
    int tv = (tid >= s) ? sd[tid - s] : 0;
    __syncthreads();
    sd[tid] += tv;
    __syncthreads();
  }
  if (i < N) offs[i] = sd[tid] - v;  // local exclusive
  if (tid == 1023) bsum[blockIdx.x] = sd[1023];
}

__global__ void scan2(int* __restrict__ bsum, int* __restrict__ offs, int nb, int N, int E) {
  if (threadIdx.x == 0) {
    int r = 0;
    for (int i = 0; i < nb; i++) { int v = bsum[i]; bsum[i] = r; r += v; }
    offs[N] = E;
  }
}

__global__ void scan3(int* __restrict__ offs, const int* __restrict__ bsum, int N) {
  int i = blockIdx.x * 1024 + threadIdx.x;
  if (i < N) offs[i] += bsum[blockIdx.x];
}

__global__ void scatter_kernel(const int* __restrict__ src, const int* __restrict__ dst,
                               const int* __restrict__ off, int* __restrict__ cur,
                               int* __restrict__ srcp, int E) {
  int t = blockIdx.x * 256 + threadIdx.x;
  if (t < E) {
    int d = dst[t];
    int p = off[d] + atomicAdd(&cur[d], 1);
    srcp[p] = src[t];
  }
}

// ---------------- fp32 -> f16 converts ----------------

__global__ void convX(const float* __restrict__ x, _Float16* __restrict__ xh, int n4) {
  int i = blockIdx.x * 256 + threadIdx.x;
  if (i >= n4) return;
  float4 v = ((const float4*)x)[i];
  h4v h;
  h[0] = (_Float16)v.x; h[1] = (_Float16)v.y;
  h[2] = (_Float16)v.z; h[3] = (_Float16)v.w;
  ((h4v*)xh)[i] = h;
}

// W [K][512] f32 -> Wt [512][K] f16 transposed, coalesced via LDS tile.
__global__ void convW(const float* __restrict__ W, _Float16* __restrict__ Th, int K) {
  __shared__ float tile[32][33];
  int bx = blockIdx.x * 32;  // output-col base (N=512 dim)
  int by = blockIdx.y * 32;  // k base
  int tx = threadIdx.x, ty = threadIdx.y;
#pragma unroll
  for (int i = 0; i < 32; i += 8)
    tile[ty + i][tx] = W[(size_t)(by + ty + i) * 512 + bx + tx];
  __syncthreads();
#pragma unroll
  for (int i = 0; i < 32; i += 8)
    Th[(size_t)(bx + ty + i) * K + by + tx] = (_Float16)tile[tx][ty + i];
}

// Ws3 [512][16] -> Bt [16][512]
__global__ void convW3(const float* __restrict__ W, _Float16* __restrict__ Th) {
  int t = blockIdx.x * 256 + threadIdx.x;
  if (t >= 512 * 16) return;
  int k = t >> 4, c = t & 15;
  Th[c * 512 + k] = (_Float16)W[t];
}

// ---------------- f16 MFMA GEMM, 3-buffer counted-vmcnt pipeline, fused als ------------
// C[M,512](f16) = A[M,K](f16) @ B[K,512]; B transposed [512][K] f16.
// 128x128 tile, BK=32, 4 waves (2x2), 16x16x32 mfma. r9-proven main loop:
// 3 x 16KB LDS buffers; one raw s_barrier per K-step; counted s_waitcnt vmcnt(4)
// keeps the next tile's loads in flight across the barrier.
// NEW epilogue: C-tile staged in LDS (stride 136 f16), then fully-coalesced
// b128 reads + dwordx4 stores (replaces 64 scalar 2B global stores per thread).
// Fused: als[row, cn>>7] = sum_col C[row,col]*a_s[col]. Bijective XCD swizzle (m204).

#define STAGE(bs, kt)                                  \
  do {                                                 \
    const size_t ko = (size_t)(kt) + w * 8;            \
    char* d0 = sm + (bs) + (w * 128) * 16;             \
    char* d1 = d0 + 1024;                              \
    gll16(A + (tm + l) * K + ko,      d0);             \
    gll16(A + (tm + 64 + l) * K + ko, d1);             \
    gll16(Bh + (cn + l) * K + ko,      d0 + 8192);     \
    gll16(Bh + (cn + 64 + l) * K + ko, d1 + 8192);     \
  } while (0)

template <int K>
__global__ __launch_bounds__(256) void gemm_f16(
    const _Float16* __restrict__ A, const _Float16* __restrict__ Bh,
    const float* __restrict__ a_s, _Float16* __restrict__ C,
    float* __restrict__ als, int M) {
  __shared__ __align__(16) char sm[49152];  // 3 x 16KB; epilogue reuses as C-stage
  const int t = threadIdx.x;
  const int w = t >> 6, l = t & 63;
  const int wr = w >> 1, wc = w & 1;
  const int kg = l >> 4, rr = l & 15;

  // bijective XCD swizzle
  const int nwg = gridDim.x;
  const int q = nwg >> 3, r = nwg & 7;
  const int orig = blockIdx.x;
  const int xcd = orig & 7, slot = orig >> 3;
  const int wgid = (xcd < r ? xcd * (q + 1) : r * (q + 1) + (xcd - r) * q) + slot;
  const size_t tm = (size_t)(wgid >> 2) * 128;
  const size_t cn = (size_t)(wgid & 3) * 128;

  f4v acc[4][4];
#pragma unroll
  for (int i = 0; i < 4; i++)
#pragma unroll
    for (int j = 0; j < 4; j++) acc[i][j] = (f4v){0.f, 0.f, 0.f, 0.f};

  // prologue: stage first two K-tiles (8 loads outstanding per wave)
  STAGE(0, 0);
  STAGE(16384, 32);
  int o_cur = 0, o_nxt = 16384, o_3rd = 32768;

#pragma unroll 4
  for (int kt = 0; kt < K; kt += 32) {
    if (kt + 32 < K) {
      asm volatile("s_waitcnt vmcnt(4)" ::: "memory");  // cur's 4 landed; nxt in flight
    } else {
      asm volatile("s_waitcnt vmcnt(0)" ::: "memory");  // last tile: full drain
    }
    __builtin_amdgcn_sched_barrier(0);
    __builtin_amdgcn_s_barrier();   // all waves' cur-loads landed; readers of o_3rd done
    if (kt + 64 < K) STAGE(o_3rd, kt + 64);  // overlaps this step's MFMA

    const char* base = sm + o_cur;
    h8v ah[4], bh[4];
#pragma unroll
    for (int i = 0; i < 4; i++) {
      int ca = (kg * 128 + wr * 64 + i * 16 + rr) * 16;
      int cb = (kg * 128 + wc * 64 + i * 16 + rr) * 16;
      ah[i] = *(const h8v*)(base + ca);
      bh[i] = *(const h8v*)(base + 8192 + cb);
    }
#pragma unroll
    for (int i = 0; i < 4; i++)
#pragma unroll
      for (int j = 0; j < 4; j++)
        acc[i][j] = __builtin_amdgcn_mfma_f32_16x16x32_f16(ah[i], bh[j], acc[i][j], 0, 0, 0);

    int tmp = o_cur; o_cur = o_nxt; o_nxt = o_3rd; o_3rd = tmp;
  }

  // ---- epilogue ----
  // als partials (registers only): C/D layout col=lane&15, row=(lane>>4)*4+reg
  float sp[16];
#pragma unroll
  for (int k = 0; k < 16; k++) sp[k] = 0.f;
#pragma unroll
  for (int i = 0; i < 4; i++)
#pragma unroll
    for (int j = 0; j < 4; j++) {
      float aw = a_s[cn + wc * 64 + j * 16 + rr];
#pragma unroll
      for (int r2 = 0; r2 < 4; r2++) sp[i * 4 + r2] += acc[i][j][r2] * aw;
    }
#pragma unroll
  for (int o = 1; o < 16; o <<= 1)
#pragma unroll
    for (int k = 0; k < 16; k++) sp[k] += __shfl_xor(sp[k], o);

  __syncthreads();  // all waves done with K-loop LDS
  // stage C-tile into LDS: [128][136] f16 (272B row stride -> 4-bank row shift)
  _Float16* ct = (_Float16*)sm;
#pragma unroll
  for (int i = 0; i < 4; i++) {
    int row0 = wr * 64 + i * 16 + kg * 4;
#pragma unroll
    for (int j = 0; j < 4; j++) {
      int col = wc * 64 + j * 16 + rr;
#pragma unroll
      for (int r2 = 0; r2 < 4; r2++) ct[(row0 + r2) * 136 + col] = (_Float16)acc[i][j][r2];
    }
  }
  float* ap = (float*)(sm + 34816);  // als cross-wave combine region
  if (wc == 0 && rr == 0) {
#pragma unroll
    for (int k = 0; k < 16; k++)
      ap[wr * 64 + (k >> 2) * 16 + kg * 4 + (k & 3)] = sp[k];
  }
  __syncthreads();
  // coalesced C write: 2 threads per row, 8x b128 each
  {
    int row = t >> 1, half = t & 1;
    size_t grow = tm + row;
    if (grow < (size_t)M) {
      const _Float16* srow = ct + row * 136 + half * 64;
      _Float16* drow = C + grow * 512 + cn + half * 64;
#pragma unroll
      for (int qq = 0; qq < 8; qq++)
        *(h8v*)(drow + qq * 8) = *(const h8v*)(srow + qq * 8);
    }
  }
  if (wc == 1 && rr == 0) {
    int head = (int)(cn >> 7);
#pragma unroll
    for (int k = 0; k < 16; k++) {
      int row = wr * 64 + (k >> 2) * 16 + kg * 4 + (k & 3);
      size_t grow = tm + row;
      if (grow < (size_t)M) als[grow * 4 + head] = ap[row] + sp[k];
    }
  }
}

// ---------------- layer-3 projection via MFMA + fused als3 ----------------
// C[M,16](f32) = A[M,512] @ B[512,16]; one wave per 16-row tile; B^T [16][512] f16.

__global__ __launch_bounds__(256) void gemm3(const _Float16* __restrict__ A,
                                             const _Float16* __restrict__ Bth,
                                             const float* __restrict__ as3,
                                             float* __restrict__ C,
                                             float* __restrict__ als, int M) {
  int wv = threadIdx.x >> 6, l = threadIdx.x & 63;
  size_t tm = ((size_t)blockIdx.x * 4 + wv) * 16;
  if (tm >= (size_t)M) return;
  int rr = l & 15, kg = l >> 4;
  f4v acc = (f4v){0.f, 0.f, 0.f, 0.f};
  for (int kt = 0; kt < 512; kt += 32) {
    int ka = kt + kg * 8;
    h8v a_h = *(const h8v*)&A[(tm + rr) * 512 + ka];
    h8v b_h = *(const h8v*)&Bth[rr * 512 + ka];
    acc = __builtin_amdgcn_mfma_f32_16x16x32_f16(a_h, b_h, acc, 0, 0, 0);
  }
  float aw = as3[rr];
  float s[4];
#pragma unroll
  for (int r = 0; r < 4; r++) s[r] = acc[r] * aw;
#pragma unroll
  for (int o = 1; o < 16; o <<= 1)
#pragma unroll
    for (int r = 0; r < 4; r++) s[r] += __shfl_xor(s[r], o);
#pragma unroll
  for (int r = 0; r < 4; r++) {
    size_t row = tm + kg * 4 + r;
    if (row < (size_t)M) {
      C[row * 16 + rr] = acc[r];
      if (rr == 0) als[row] = s[r];
    }
  }
}

// ---------------- wsd[k][h] = sum_c Wd[k][h*C+c] * a_d[h][c] ----------------

__global__ void wsd_kernel(const float* __restrict__ Wd, const float* __restrict__ a_d,
                           float* __restrict__ wsd, int K, int H, int C) {
  int g = (blockIdx.x * 256 + threadIdx.x) >> 4;
  int l16 = threadIdx.x & 15;
  if (g >= K * H) return;
  int k = g / H, h = g - k * H;
  int ce = C >> 4;
  float s = 0.f;
  for (int j = 0; j < ce; j++) {
    int c = l16 * ce + j;
    s += Wd[(size_t)k * (H * C) + h * C + c] * a_d[h * C + c];
  }
#pragma unroll
  for (int o = 1; o < 16; o <<= 1) s += __shfl_xor(s, o);
  if (l16 == 0) wsd[k * H + h] = s;
}

// ---------------- per-edge normalized softmax weights ----------------
// Layer 1 (H=4, K=128): one wave per node, lane = e*4+h; ald computed in-kernel
// from own x-row (cheap: [N,128] f16 = 12.8 MB).

__global__ void wgt4_kernel(const float* __restrict__ als, const _Float16* __restrict__ hin,
                            const float* __restrict__ wsd, const int* __restrict__ off,
                            const int* __restrict__ srcp, _Float16* __restrict__ wgt, int N) {
  int wid = threadIdx.x >> 6, lane = threadIdx.x & 63;
  int n = blockIdx.x * 4 + wid;
  if (n >= N) return;
  int p0 = off[n], deg = off[n + 1] - p0;
  if (deg == 0) return;

  float d0 = 0.f, d1 = 0.f, d2 = 0.f, d3 = 0.f;
  {
    int k0 = lane * 2;
    h2v qv = *(const h2v*)&hin[(size_t)n * 128 + k0];
#pragma unroll
    for (int j = 0; j < 2; j++) {
      float xv = (float)qv[j];
      float4 wv = *(const float4*)&wsd[(k0 + j) * 4];
      d0 += xv * wv.x; d1 += xv * wv.y; d2 += xv * wv.z; d3 += xv * wv.w;
    }
#pragma unroll
    for (int o = 1; o < 64; o <<= 1) {
      d0 += __shfl_xor(d0, o); d1 += __shfl_xor(d1, o);
      d2 += __shfl_xor(d2, o); d3 += __shfl_xor(d3, o);
    }
  }
  int h = lane & 3, e = lane >> 2;
  float aldn = (h == 0) ? d0 : (h == 1) ? d1 : (h == 2) ? d2 : d3;

  float ev0 = -1e30f;
  if (e < deg) {
    float v = als[srcp[p0 + e] * 4 + h] + aldn;
    ev0 = (v > 0.f) ? v : NEG_SLOPE * v;
  }
  float m = ev0;
  for (int base = 16; base < deg; base += 16) {
    float ev = -1e30f;
    if (base + e < deg) {
      float v = als[srcp[p0 + base + e] * 4 + h] + aldn;
      ev = (v > 0.f) ? v : NEG_SLOPE * v;
    }
    m = fmaxf(m, ev);
  }
#pragma unroll
  for (int o = 4; o < 64; o <<= 1) m = fmaxf(m, __shfl_xor(m, o));
  float den = (e < deg) ? __expf(ev0 - m) : 0.f;
  for (int base = 16; base < deg; base += 16) {
    if (base + e < deg) {
      float v = als[srcp[p0 + base + e] * 4 + h] + aldn;
      v = (v > 0.f) ? v : NEG_SLOPE * v;
      den += __expf(v - m);
    }
  }
#pragma unroll
  for (int o = 4; o < 64; o <<= 1) den += __shfl_xor(den, o);
  float rw = 1.f / (den + EPSF);
  if (e < deg) wgt[(size_t)(p0 + e) * 4 + h] = (_Float16)(__expf(ev0 - m) * rw);
  for (int base = 16; base < deg; base += 16) {
    if (base + e < deg) {
      float v = als[srcp[p0 + base + e] * 4 + h] + aldn;
      v = (v > 0.f) ? v : NEG_SLOPE * v;
      wgt[(size_t)(p0 + base + e) * 4 + h] = (_Float16)(__expf(v - m) * rw);
    }
  }
}

// Layer 2 (H=4): ald precomputed by layer-1 agg512 -> no h re-read.
__global__ void wgt4p_kernel(const float* __restrict__ als, const float* __restrict__ ald,
                             const int* __restrict__ off, const int* __restrict__ srcp,
                             _Float16* __restrict__ wgt, int N) {
  int wid = threadIdx.x >> 6, lane = threadIdx.x & 63;
  int n = blockIdx.x * 4 + wid;
  if (n >= N) return;
  int p0 = off[n], deg = off[n + 1] - p0;
  if (deg == 0) return;
  int h = lane & 3, e = lane >> 2;
  float aldn = ald[n * 4 + h];

  float ev0 = -1e30f;
  if (e < deg) {
    float v = als[srcp[p0 + e] * 4 + h] + aldn;
    ev0 = (v > 0.f) ? v : NEG_SLOPE * v;
  }
  float m = ev0;
  for (int base = 16; base < deg; base += 16) {
    float ev = -1e30f;
    if (base + e < deg) {
      float v = als[srcp[p0 + base + e] * 4 + h] + aldn;
      ev = (v > 0.f) ? v : NEG_SLOPE * v;
    }
    m = fmaxf(m, ev);
  }
#pragma unroll
  for (int o = 4; o < 64; o <<= 1) m = fmaxf(m, __shfl_xor(m, o));
  float den = (e < deg) ? __expf(ev0 - m) : 0.f;
  for (int base = 16; base < deg; base += 16) {
    if (base + e < deg) {
      float v = als[srcp[p0 + base + e] * 4 + h] + aldn;
      v = (v > 0.f) ? v : NEG_SLOPE * v;
      den += __expf(v - m);
    }
  }
#pragma unroll
  for (int o = 4; o < 64; o <<= 1) den += __shfl_xor(den, o);
  float rw = 1.f / (den + EPSF);
  if (e < deg) wgt[(size_t)(p0 + e) * 4 + h] = (_Float16)(__expf(ev0 - m) * rw);
  for (int base = 16; base < deg; base += 16) {
    if (base + e < deg) {
      float v = als[srcp[p0 + base + e] * 4 + h] + aldn;
      v = (v > 0.f) ? v : NEG_SLOPE * v;
      wgt[(size_t)(p0 + base + e) * 4 + h] = (_Float16)(__expf(v - m) * rw);
    }
  }
}

// Layer 3 (H=1): ald3 precomputed by layer-2 agg512.
__global__ void wgt1p_kernel(const float* __restrict__ als, const float* __restrict__ ald,
                             const int* __restrict__ off, const int* __restrict__ srcp,
                             _Float16* __restrict__ wgt, int N) {
  int wid = threadIdx.x >> 6, lane = threadIdx.x & 63;
  int n = blockIdx.x * 4 + wid;
  if (n >= N) return;
  int p0 = off[n], deg = off[n + 1] - p0;
  if (deg == 0) return;
  float aldn = ald[n];

  float ev0 = -1e30f;
  if (lane < deg) {
    float v = als[srcp[p0 + lane]] + aldn;
    ev0 = (v > 0.f) ? v : NEG_SLOPE * v;
  }
  float m = ev0;
  for (int base = 64; base < deg; base += 64) {
    float ev = -1e30f;
    if (base + lane < deg) {
      float v = als[srcp[p0 + base + lane]] + aldn;
      ev = (v > 0.f) ? v : NEG_SLOPE * v;
    }
    m = fmaxf(m, ev);
  }
#pragma unroll
  for (int o = 1; o < 64; o <<= 1) m = fmaxf(m, __shfl_xor(m, o));
  float den = (lane < deg) ? __expf(ev0 - m) : 0.f;
  for (int base = 64; base < deg; base += 64) {
    if (base + lane < deg) {
      float v = als[srcp[p0 + base + lane]] + aldn;
      v = (v > 0.f) ? v : NEG_SLOPE * v;
      den += __expf(v - m);
    }
  }
#pragma unroll
  for (int o = 1; o < 64; o <<= 1) den += __shfl_xor(den, o);
  float rw = 1.f / (den + EPSF);
  if (lane < deg) wgt[p0 + lane] = (_Float16)(__expf(ev0 - m) * rw);
  for (int base = 64; base < deg; base += 64) {
    if (base + lane < deg) {
      float v = als[srcp[p0 + base + lane]] + aldn;
      v = (v > 0.f) ? v : NEG_SLOPE * v;
      wgt[p0 + base + lane] = (_Float16)(__expf(v - m) * rw);
    }
  }
}

// ---------------- aggregation + fused next-layer ald ----------------
// one 128-thread block per node, thread t handles channels 4t..4t+3.
// HN=4: also computes ald_next[n,0..3] = relu(h)·wsdn ([512,4]).
// HN=1: also computes ald_next[n] = relu(h)·wsdn ([512]).

template <int HN>
__global__ __launch_bounds__(128) void agg512(
    const _Float16* __restrict__ xs, const _Float16* __restrict__ wgt,
    const int* __restrict__ off, const int* __restrict__ srcp,
    const float* __restrict__ bias, const float* __restrict__ wsdn,
    _Float16* __restrict__ oh, float* __restrict__ aldo, int N) {
  __shared__ float red[8];
  int n = blockIdx.x;
  int t = threadIdx.x;
  int h = t >> 5;  // channel 4t -> head 4t/128
  int p0 = off[n], p1 = off[n + 1];
  float a0 = 0.f, a1 = 0.f, a2 = 0.f, a3 = 0.f;
  float c0 = 0.f, c1 = 0.f, c2 = 0.f, c3 = 0.f;
  int p = p0;
  for (; p + 1 < p1; p += 2) {
    int s0 = srcp[p], s1 = srcp[p + 1];
    float w0 = (float)wgt[(size_t)p * 4 + h];
    float w1 = (float)wgt[(size_t)(p + 1) * 4 + h];
    h4v v0 = *(const h4v*)&xs[(size_t)s0 * 512 + 4 * t];
    h4v v1 = *(const h4v*)&xs[(size_t)s1 * 512 + 4 * t];
    a0 += w0 * (float)v0[0]; a1 += w0 * (float)v0[1];
    a2 += w0 * (float)v0[2]; a3 += w0 * (float)v0[3];
    c0 += w1 * (float)v1[0]; c1 += w1 * (float)v1[1];
    c2 += w1 * (float)v1[2]; c3 += w1 * (float)v1[3];
  }
  if (p < p1) {
    int s0 = srcp[p];
    float w0 = (float)wgt[(size_t)p * 4 + h];
    h4v v0 = *(const h4v*)&xs[(size_t)s0 * 512 + 4 * t];
    a0 += w0 * (float)v0[0]; a1 += w0 * (float)v0[1];
    a2 += w0 * (float)v0[2]; a3 += w0 * (float)v0[3];
  }
  a0 += c0; a1 += c1; a2 += c2; a3 += c3;
  float4 b = *(const float4*)&bias[4 * t];
  a0 = fmaxf(a0 + b.x, 0.f); a1 = fmaxf(a1 + b.y, 0.f);
  a2 = fmaxf(a2 + b.z, 0.f); a3 = fmaxf(a3 + b.w, 0.f);
  h4v wh;
  wh[0] = (_Float16)a0; wh[1] = (_Float16)a1;
  wh[2] = (_Float16)a2; wh[3] = (_Float16)a3;
  *(h4v*)&oh[(size_t)n * 512 + 4 * t] = wh;

  if constexpr (HN == 4) {
    float4 w0 = ((const float4*)wsdn)[4 * t + 0];
    float4 w1 = ((const float4*)wsdn)[4 * t + 1];
    float4 w2 = ((const float4*)wsdn)[4 * t + 2];
    float4 w3 = ((const float4*)wsdn)[4 * t + 3];
    float p0h = a0 * w0.x + a1 * w1.x + a2 * w2.x + a3 * w3.x;
    float p1h = a0 * w0.y + a1 * w1.y + a2 * w2.y + a3 * w3.y;
    float p2h = a0 * w0.z + a1 * w1.z + a2 * w2.z + a3 * w3.z;
    float p3h = a0 * w0.w + a1 * w1.w + a2 * w2.w + a3 * w3.w;
#pragma unroll
    for (int o = 1; o < 64; o <<= 1) {
      p0h += __shfl_xor(p0h, o); p1h += __shfl_xor(p1h, o);
      p2h += __shfl_xor(p2h, o); p3h += __shfl_xor(p3h, o);
    }
    if ((t & 63) == 0) {
      int wv = t >> 6;
      red[wv * 4 + 0] = p0h; red[wv * 4 + 1] = p1h;
      red[wv * 4 + 2] = p2h; red[wv * 4 + 3] = p3h;
    }
    __syncthreads();
    if (t == 0) {
      float4 rr;
      rr.x = red[0] + red[4]; rr.y = red[1] + red[5];
      rr.z = red[2] + red[6]; rr.w = red[3] + red[7];
      *(float4*)&aldo[(size_t)n * 4] = rr;
    }
  } else if constexpr (HN == 1) {
    float4 wv4 = *(const float4*)&wsdn[4 * t];
    float ph = a0 * wv4.x + a1 * wv4.y + a2 * wv4.z + a3 * wv4.w;
#pragma unroll
    for (int o = 1; o < 64; o <<= 1) ph += __shfl_xor(ph, o);
    if ((t & 63) == 0) red[t >> 6] = ph;
    __syncthreads();
    if (t == 0) aldo[n] = red[0] + red[1];
  }
}

// layer 3: H=1, C=16, no relu, f32 out. 16 nodes per block.
__global__ void agg16(const float* __restrict__ xs3, const _Float16* __restrict__ wgt,
                      const int* __restrict__ off, const int* __restrict__ srcp,
                      const float* __restrict__ bias, float* __restrict__ out, int N) {
  int g = threadIdx.x >> 4, c = threadIdx.x & 15;
  int n = blockIdx.x * 16 + g;
  if (n >= N) return;
  int p0 = off[n], p1 = off[n + 1];
  float acc = 0.f;
  for (int p = p0; p < p1; p++)
    acc += (float)wgt[p] * xs3[(size_t)srcp[p] * 16 + c];
  out[(size_t)n * 16 + c] = acc + bias[c];
}

// ---------------- launch ----------------

extern "C" void kernel_launch(void* const* d_in, const int* in_sizes, int n_in,
                              void* d_out, int out_size, void* d_ws, size_t ws_size,
                              hipStream_t stream) {
  const float* x   = (const float*)d_in[0];
  const int*   ei  = (const int*)d_in[1];
  const float* Ws1 = (const float*)d_in[2];
  const float* Wd1 = (const float*)d_in[3];
  const float* as1 = (const float*)d_in[4];
  const float* ad1 = (const float*)d_in[5];
  const float* b1  = (const float*)d_in[6];
  const float* Ws2 = (const float*)d_in[7];
  const float* Wd2 = (const float*)d_in[8];
  const float* as2 = (const float*)d_in[9];
  const float* ad2 = (const float*)d_in[10];
  const float* b2  = (const float*)d_in[11];
  const float* Ws3 = (const float*)d_in[12];
  const float* Wd3 = (const float*)d_in[13];
  const float* as3 = (const float*)d_in[14];
  const float* ad3 = (const float*)d_in[15];
  const float* b3  = (const float*)d_in[16];

  const int N = in_sizes[0] / 128;  // 50000
  const int E = in_sizes[1] / 2;    // 400000
  const int* src = ei;
  const int* dst = ei + E;

  // workspace layout (bytes), total ~115 MB; all offsets 16B-aligned
  char* w = (char*)d_ws;
  _Float16* xs     = (_Float16*)(w + 0);           // [N,512] f16
  _Float16* hbuf   = (_Float16*)(w + 51200000);    // [N,512] f16 ([N,128] x_f16 early)
  float*    als    = (float*)(w + 102400000);      // [N,4] (layer3: [N] flat)
  float*    ald    = (float*)(w + 103200000);      // [N,4] (layer3: [N] flat)
  float*    xs3    = (float*)(w + 104000000);      // [N,16] f32
  _Float16* wgt    = (_Float16*)(w + 107200000);   // [E,4] f16
  int*      counts = (int*)(w + 110400000);        // [N]
  int*      cur    = (int*)(w + 110600000);        // [N]
  int*      offs   = (int*)(w + 110800000);        // [N+1]
  int*      bsum   = (int*)(w + 111000192);        // [~49]
  int*      srcp   = (int*)(w + 111004288);        // [E]
  float*    wsd1   = (float*)(w + 112604288);      // [128,4]
  float*    wsd2   = (float*)(w + 112606336);      // [512,4]
  float*    wsd3   = (float*)(w + 112614528);      // [512]
  _Float16* wt_hi  = (_Float16*)(w + 112616576);   // [512,512] f16 (B^T)
  _Float16* wt3_hi = (_Float16*)(w + 113140864);   // [16,512] f16

  // ---- CSR build ----
  hipMemsetAsync(counts, 0, 2 * (size_t)N * 4, stream);  // counts + cur contiguous
  hist_kernel<<<(E + 255) / 256, 256, 0, stream>>>(dst, counts, E);
  int nb = (N + 1023) / 1024;
  scan1<<<nb, 1024, 0, stream>>>(counts, offs, bsum, N);
  scan2<<<1, 64, 0, stream>>>(bsum, offs, nb, N, E);
  scan3<<<nb, 1024, 0, stream>>>(offs, bsum, N);
  scatter_kernel<<<(E + 255) / 256, 256, 0, stream>>>(src, dst, offs, cur, srcp, E);

  int ggrid = ((N + 127) / 128) * 4;  // 1-D grid; XCD swizzle inside kernel
  dim3 cwb(32, 8);
  int nwb = (N + 3) / 4;

  // ---- weight preprocessing (wsd needed before each layer's agg) ----
  wsd_kernel<<<(128 * 4 * 16 + 255) / 256, 256, 0, stream>>>(Wd1, ad1, wsd1, 128, 4, 128);
  wsd_kernel<<<(512 * 4 * 16 + 255) / 256, 256, 0, stream>>>(Wd2, ad2, wsd2, 512, 4, 128);
  wsd_kernel<<<(512 * 16 + 255) / 256, 256, 0, stream>>>(Wd3, ad3, wsd3, 512, 1, 16);

  // ---- layer 1 (K=128) ----
  convX<<<(N * 128 / 4 + 255) / 256, 256, 0, stream>>>(x, hbuf, N * 128 / 4);
  convW<<<dim3(16, 4), cwb, 0, stream>>>(Ws1, wt_hi, 128);
  gemm_f16<128><<<ggrid, 256, 0, stream>>>(hbuf, wt_hi, as1, xs, als, N);
  wgt4_kernel<<<nwb, 256, 0, stream>>>(als, hbuf, wsd1, offs, srcp, wgt, N);
  agg512<4><<<N, 128, 0, stream>>>(xs, wgt, offs, srcp, b1, wsd2, hbuf, ald, N);

  // ---- layer 2 (K=512) ----
  convW<<<dim3(16, 16), cwb, 0, stream>>>(Ws2, wt_hi, 512);
  gemm_f16<512><<<ggrid, 256, 0, stream>>>(hbuf, wt_hi, as2, xs, als, N);
  wgt4p_kernel<<<nwb, 256, 0, stream>>>(als, ald, offs, srcp, wgt, N);
  agg512<1><<<N, 128, 0, stream>>>(xs, wgt, offs, srcp, b2, wsd3, hbuf, ald, N);

  // ---- layer 3 (K=512, N=16, H=1) ----
  convW3<<<32, 256, 0, stream>>>(Ws3, wt3_hi);
  gemm3<<<(N / 16 + 4) / 4, 256, 0, stream>>>(hbuf, wt3_hi, as3, xs3, als, N);
  wgt1p_kernel<<<nwb, 256, 0, stream>>>(als, ald, offs, srcp, wgt, N);
  agg16<<<(N + 15) / 16, 256, 0, stream>>>(xs3, wgt, offs, srcp, b3, (float*)d_out, N);
}